// Round 6
// baseline (941.909 us; speedup 1.0000x reference)
//
#include <hip/hip_runtime.h>
#include <hip/hip_bf16.h>
#include <cstdint>
#include <cstddef>

#define HIDDEN 2048
#define INTER 8192
#define M_TOK 8192   // BATCH * LOCAL_SEQ = 2 * 4096

typedef __attribute__((ext_vector_type(8))) short short8;   // 8 bf16 = 4 VGPRs
typedef __attribute__((ext_vector_type(4))) float float4v;  // MFMA C/D

typedef __hip_bfloat16 bf16;

// ---------------------------------------------------------------------------
// fp32 -> bf16 convert (memory-bound, grid-stride)
// ---------------------------------------------------------------------------
__global__ void cvt_bf16(const float* __restrict__ src, bf16* __restrict__ dst, int n) {
    int idx = blockIdx.x * blockDim.x + threadIdx.x;
    int stride = gridDim.x * blockDim.x;
    for (int i = idx * 4; i < n; i += stride * 4) {
        float4 v = *(const float4*)(src + i);
        union { bf16 h[4]; ushort4 u; } pk;
        pk.h[0] = __float2bfloat16(v.x);
        pk.h[1] = __float2bfloat16(v.y);
        pk.h[2] = __float2bfloat16(v.z);
        pk.h[3] = __float2bfloat16(v.w);
        *(ushort4*)(dst + i) = pk.u;
    }
}

// async global->LDS, 16B per lane; LDS dest = wave-uniform base + lane*16
__device__ __forceinline__ void load16_lds(const bf16* g, bf16* l) {
    __builtin_amdgcn_global_load_lds((const __attribute__((address_space(1))) void*)g,
                                     (__attribute__((address_space(3))) void*)l,
                                     16, 0, 0);
}

// ---------------------------------------------------------------------------
// 256x256-tile, BK=64, 8-wave, double-buffered 128 KiB LDS.
// R6: dead-register read-ahead. R4/R5 measured phase = LDS_time + MFMA_time
// (serial, 4144/4270 cyc/tile vs 2483 MFMA floor) because reads and MFMA
// never co-occupied their pipes. Now every phase's reads target registers
// that are DEAD in that phase's cluster, issued between BAR and MFMA:
// the LDS pipe drains them under the cluster; consumers are >=1 phase later.
//
// Quadrant order (0,0),(0,1),(1,1),(1,0):  A0: p0,p1 | B1: p1,p2 | A1: p2,p3
// | B0: p0,p3 (the one tile-wrapping operand -> only B0 is double-set).
//   p0 (af=A0 x b0c): front-read B1(kt) -> b1q      [4]  (b1q dead)
//   p1 (af=A0 x b1q): i2-interleaved A1(kt) -> af   [8]  (af[i2] dies per group)
//   p2 (af=A1 x b1q): front-read B0(kt+1) -> b0n    [4]  (other B0 set, dead)
//   p3 (af=A1 x b0c): i2-interleaved A0(kt+1) -> af [8]  (from NEXT buf)
// Registers: af 32 + b0 ping-pong 32 + b1q 16 = 80 frag VGPRs (+16 vs R5),
// offset by staged-pointer refactor (8 ptrs -> 2 bases + constexpr offsets).
//
// Stage/wait ledger (stages: p0 B0', p1 A0', p2 B1', p3 A1'; FIFO-verified):
//   entry [B1(kt), A1(kt)];  p0 +B0' vmcnt(4) ret B1(kt)  -> read p0 ✓
//   p1 +A0' vmcnt(4) ret A1(kt) -> read p1 ✓ ; p2 +B1' vmcnt(4) ret B0' ✓
//   p3 +A1' vmcnt(4) ret A0' ✓ ; exit [B1', A1'] = entry(kt+1) ✓
// Uniform vmcnt(4); every stage->forced-retire slack = 2 phases; every read
// covered by {own-vmcnt -> barrier}; in-flight 4..6, never 0.
// WAR: af overwrites are group-wise after last use (reg-dep enforced);
// LDS buffer overwrite trails last read by >= 2 barriers (checked both
// parities).  LDS row permutation + XOR swizzle unchanged (conflicts = 0).
// ---------------------------------------------------------------------------
template<int KDIM, bool FUSE>
__global__ __launch_bounds__(512, 2) void gemm_8ph(const bf16* __restrict__ A,
                                                   const bf16* __restrict__ B,
                                                   bf16* __restrict__ actout,
                                                   float* __restrict__ cout) {
    static_assert(KDIM % 128 == 0, "KDIM multiple of 128 (tile pairs)");
    __shared__ __align__(16) bf16 sm[2 * 32768];   // 131072 B

    constexpr int NKT = KDIM / 64;

    const int tid  = threadIdx.x;
    const int wave = tid >> 6;
    const int lane = tid & 63;
    const int wm = wave >> 2;          // 0..1 : M-half of C
    const int wn = wave & 3;           // 0..3 : N-quarter of C
    const int lm = lane & 15;
    const int kg = lane >> 4;

    // XCD-aware swizzle: id&7 = XCD; same-A-panel blocks share one XCD L2.
    const int id = blockIdx.y * gridDim.x + blockIdx.x;
    const int w_ = id >> 3;
    const int by = (id & 7) * 4 + (w_ & 3);
    const int bx = w_ >> 2;

    const int m0 = by * 256;
    const int n0 = bx * (FUSE ? 128 : 256);

    // ---- staging: issue q writes LDS phys rows q*64..q*64+63 (perm source) --
    const int srow = wave * 8 + (lane >> 3);
    const int scol = ((lane & 7) ^ (lane >> 3)) * 8;   // pre-swizzled k-chunk

    const bf16* const aBase = A + (size_t)(m0 + srow) * KDIM + scol;
    const int brow0 = FUSE ? (n0 + srow)
                           : (n0 + ((srow >> 5) << 6) + (srow & 31));
    const bf16* const bBase = B + (size_t)brow0 * KDIM + scol;

// per-issue uniform row offsets (elements), derived from the R1 permutation
#define AOFFQ(q) ((size_t)((((q) & 1) * 128 + ((q) >> 1) * 64)) * KDIM)
#define BOFFQ(q) (FUSE ? ((size_t)(((q) >> 1) ? (INTER + ((q) & 1) * 64) \
                                              : (((q) & 1) * 64)) * KDIM) \
                       : ((size_t)((((q) & 1) * 128 + ((q) >> 1) * 32)) * KDIM))

    bf16* const sdA = sm + wave * 512;
    bf16* const sdB = sm + 16384 + wave * 512;

    const int sl0 = ((0 * 4 + kg) ^ (lm & 7)) * 8;   // ks = 0 slot
    const int sl1 = ((1 * 4 + kg) ^ (lm & 7)) * 8;   // ks = 1 slot

    float4v acc[8][4];
#pragma unroll
    for (int i = 0; i < 8; i++)
#pragma unroll
        for (int j = 0; j < 4; j++) acc[i][j] = (float4v)0.f;

    short8 af[8];    // A slot, rotates in place: A0 -> A1 (p1) -> A0' (p3)
    short8 b0a[4];   // B0 even tiles
    short8 b0b[4];   // B0 odd tiles
    short8 b1q[4];   // B1 (fixed slot)

#define STAGE_A(h, nb, kn) { \
        load16_lds(aBase + AOFFQ((h)*2+0) + (size_t)(kn)*64, sdA + (nb)*32768 + ((h)*2+0)*4096); \
        load16_lds(aBase + AOFFQ((h)*2+1) + (size_t)(kn)*64, sdA + (nb)*32768 + ((h)*2+1)*4096); }
#define STAGE_B(h, nb, kn) { \
        load16_lds(bBase + BOFFQ((h)*2+0) + (size_t)(kn)*64, sdB + (nb)*32768 + ((h)*2+0)*4096); \
        load16_lds(bBase + BOFFQ((h)*2+1) + (size_t)(kn)*64, sdB + (nb)*32768 + ((h)*2+1)*4096); }
#define LOAD_A(dst, ih, smA_) { \
        _Pragma("unroll") \
        for (int i2 = 0; i2 < 4; i2++) { \
            const bf16* p = (smA_) + ((ih) * 128 + wm * 64 + i2 * 16 + lm) * 64; \
            dst[i2*2+0] = *(const short8*)(p + sl0); \
            dst[i2*2+1] = *(const short8*)(p + sl1); } }
#define LOAD_B(dst, jh, smB_) { \
        _Pragma("unroll") \
        for (int j2 = 0; j2 < 2; j2++) { \
            const bf16* p = (smB_) + ((jh) * 128 + wn * 32 + j2 * 16 + lm) * 64; \
            dst[j2*2+0] = *(const short8*)(p + sl0); \
            dst[j2*2+1] = *(const short8*)(p + sl1); } }
#define MFMA_Q(A_, B_, ih, jh) { \
        _Pragma("unroll") \
        for (int i2 = 0; i2 < 4; i2++) \
        _Pragma("unroll") \
        for (int j2 = 0; j2 < 2; j2++) { \
            acc[(ih)*4+i2][(jh)*2+j2] = __builtin_amdgcn_mfma_f32_16x16x32_bf16(A_[i2*2+0], B_[j2*2+0], acc[(ih)*4+i2][(jh)*2+j2], 0, 0, 0); \
            acc[(ih)*4+i2][(jh)*2+j2] = __builtin_amdgcn_mfma_f32_16x16x32_bf16(A_[i2*2+1], B_[j2*2+1], acc[(ih)*4+i2][(jh)*2+j2], 0, 0, 0); } }
// 4 MFMA on af[i2], then overwrite af[i2] with the next A-half's i2-fragment.
// WAR on af pins reads after their group; SGB pins the interleave pattern.
#define MFMA_ILV(A_, B_, ih, jh, rih, smR) { \
        _Pragma("unroll") \
        for (int i2 = 0; i2 < 4; i2++) { \
            acc[(ih)*4+i2][(jh)*2+0] = __builtin_amdgcn_mfma_f32_16x16x32_bf16(A_[i2*2+0], B_[0], acc[(ih)*4+i2][(jh)*2+0], 0, 0, 0); \
            acc[(ih)*4+i2][(jh)*2+0] = __builtin_amdgcn_mfma_f32_16x16x32_bf16(A_[i2*2+1], B_[1], acc[(ih)*4+i2][(jh)*2+0], 0, 0, 0); \
            acc[(ih)*4+i2][(jh)*2+1] = __builtin_amdgcn_mfma_f32_16x16x32_bf16(A_[i2*2+0], B_[2], acc[(ih)*4+i2][(jh)*2+1], 0, 0, 0); \
            acc[(ih)*4+i2][(jh)*2+1] = __builtin_amdgcn_mfma_f32_16x16x32_bf16(A_[i2*2+1], B_[3], acc[(ih)*4+i2][(jh)*2+1], 0, 0, 0); \
            const bf16* p_ = (smR) + ((rih) * 128 + wm * 64 + i2 * 16 + lm) * 64; \
            A_[i2*2+0] = *(const short8*)(p_ + sl0); \
            A_[i2*2+1] = *(const short8*)(p_ + sl1); \
            __builtin_amdgcn_sched_group_barrier(0x8,   4, 0); \
            __builtin_amdgcn_sched_group_barrier(0x100, 2, 0); \
        } }
#define FENCE asm volatile("" ::: "memory")
#define BAR   do { FENCE; __builtin_amdgcn_s_barrier(); FENCE; } while (0)
#define VMC4  asm volatile("s_waitcnt vmcnt(4)" ::: "memory")
#define SBAR0 __builtin_amdgcn_sched_barrier(0)

// One K-tile: B0C = current B0 regs, B0N = next-tile B0 regs, BB = buf index.
#define TILE_BODY(B0C, B0N, BB, KN) { \
        const bf16* const smCur  = sm + (BB) * 32768; \
        const bf16* const smCurB = smCur + 16384; \
        const bf16* const smNxt  = sm + ((BB) ^ 1) * 32768; \
        const bf16* const smNxtB = smNxt + 16384; \
        /* p0: A0 x B0 ; front-read B1(kt) */ \
        STAGE_B(0, (BB) ^ 1, KN); \
        VMC4; BAR; \
        LOAD_B(b1q, 1, smCurB); \
        SBAR0; \
        __builtin_amdgcn_s_setprio(1); MFMA_Q(af, B0C, 0, 0); __builtin_amdgcn_s_setprio(0); \
        SBAR0; \
        /* p1: A0 x B1 ; interleave A1(kt) -> af */ \
        STAGE_A(0, (BB) ^ 1, KN); \
        VMC4; BAR; \
        __builtin_amdgcn_s_setprio(1); MFMA_ILV(af, b1q, 0, 1, 1, smCur); __builtin_amdgcn_s_setprio(0); \
        SBAR0; \
        /* p2: A1 x B1 ; front-read B0(kt+1) from next buf */ \
        STAGE_B(1, (BB) ^ 1, KN); \
        VMC4; BAR; \
        LOAD_B(B0N, 0, smNxtB); \
        SBAR0; \
        __builtin_amdgcn_s_setprio(1); MFMA_Q(af, b1q, 1, 1); __builtin_amdgcn_s_setprio(0); \
        SBAR0; \
        /* p3: A1 x B0 ; interleave A0(kt+1) -> af from next buf */ \
        STAGE_A(1, (BB) ^ 1, KN); \
        VMC4; BAR; \
        __builtin_amdgcn_s_setprio(1); MFMA_ILV(af, B0C, 1, 0, 0, smNxt); __builtin_amdgcn_s_setprio(0); \
        SBAR0; \
    }

    // ---- prologue: buf0 <- B0(0), A0(0), B1(0), A1(0); last two in flight --
    STAGE_B(0, 0, 0);
    STAGE_A(0, 0, 0);
    STAGE_B(1, 0, 0);
    STAGE_A(1, 0, 0);
    VMC4;                        // retires B0(0), A0(0); [B1(0), A1(0)] fly
    BAR;
    LOAD_A(af, 0, sm);           // A0(0)
    LOAD_B(b0a, 0, sm + 16384);  // B0(0)

    for (int kt = 0; kt < NKT; kt += 2) {
        const int kn1 = kt + 1;                            // even tile: no wrap
        TILE_BODY(b0a, b0b, 0, kn1);
        const int kn2 = (kt + 2 < NKT) ? (kt + 2) : 0;     // odd tile: tail wraps (dead)
        TILE_BODY(b0b, b0a, 1, kn2);
    }
    // drain dead tail prefetches before LDS dealloc at endpgm
    asm volatile("s_waitcnt vmcnt(0)" ::: "memory");

    // ---- epilogue: C/D layout col = lane&15, row = (lane>>4)*4 + reg ----
    if (FUSE) {
        const int orow = m0 + wm * 128;
        const int ocol = n0 + wn * 32;
#pragma unroll
        for (int i = 0; i < 8; i++)
#pragma unroll
            for (int j2 = 0; j2 < 2; j2++)
#pragma unroll
                for (int r = 0; r < 4; r++) {
                    const float g = acc[i][j2][r];
                    const float u = acc[i][j2 + 2][r];
                    const float a = (g / (1.f + __expf(-g))) * u;
                    actout[(size_t)(orow + i * 16 + kg * 4 + r) * INTER + ocol + j2 * 16 + lm] =
                        __float2bfloat16(a);
                }
    } else {
        const int orow = m0 + wm * 128;
        const int ocol = n0 + wn * 64;
#pragma unroll
        for (int i = 0; i < 8; i++)
#pragma unroll
            for (int j = 0; j < 4; j++)
#pragma unroll
                for (int r = 0; r < 4; r++)
                    cout[(size_t)(orow + i * 16 + kg * 4 + r) * HIDDEN + ocol + j * 16 + lm] =
                        acc[i][j][r];
    }
#undef STAGE_A
#undef STAGE_B
#undef LOAD_A
#undef LOAD_B
#undef MFMA_Q
#undef MFMA_ILV
#undef FENCE
#undef BAR
#undef VMC4
#undef SBAR0
#undef TILE_BODY
#undef AOFFQ
#undef BOFFQ
}

// ---------------------------------------------------------------------------
extern "C" void kernel_launch(void* const* d_in, const int* in_sizes, int n_in,
                              void* d_out, int out_size, void* d_ws, size_t ws_size,
                              hipStream_t stream) {
    const float* h   = (const float*)d_in[0];   // [2,4096,2048]
    const float* wgu = (const float*)d_in[1];   // [16384,2048]
    const float* wd  = (const float*)d_in[2];   // [2048,8192]
    float* out = (float*)d_out;                 // [2,4096,2048]

    char* ws = (char*)d_ws;
    bf16* hbf   = (bf16*)(ws);                   //  33,554,432 B
    bf16* wgubf = (bf16*)(ws + 33554432ull);     //  67,108,864 B
    bf16* wdbf  = (bf16*)(ws + 100663296ull);    //  33,554,432 B
    bf16* actbf = (bf16*)(ws + 134217728ull);    // 134,217,728 B

    cvt_bf16<<<dim3(4096), 256, 0, stream>>>(h,   hbf,   M_TOK * HIDDEN);
    cvt_bf16<<<dim3(8192), 256, 0, stream>>>(wgu, wgubf, 2 * INTER * HIDDEN);
    cvt_bf16<<<dim3(4096), 256, 0, stream>>>(wd,  wdbf,  HIDDEN * INTER);

    // GEMM1 + silu: x = INTER/128 = 64 col blocks, y = M_TOK/256 = 32 -> 2048 blocks
    gemm_8ph<HIDDEN, true><<<dim3(64, 32), 512, 0, stream>>>(hbf, wgubf, actbf, nullptr);

    // GEMM2: grid (HIDDEN/256 = 8, M_TOK/256 = 32) = 256 blocks = 1/CU
    gemm_8ph<INTER, false><<<dim3(8, 32), 512, 0, stream>>>(actbf, wdbf, nullptr, out);
}